// Round 2
// baseline (2105.747 us; speedup 1.0000x reference)
//
#include <hip/hip_runtime.h>

// ROIMaskHead: x[1024,14,14,256] f32 -> 4x (conv3x3 256->256 + relu) ->
// conv_transpose 2x2 s2 + relu -> 1x1 conv ->80, out [1024,28,28,80] f32.
// All matmuls via mfma_f32_16x16x32_f16; activations/weights fp16, acc f32.
// R2: 64x64 wave tiles (acc=64 -> 3 waves/SIMD), XOR-swizzled LDS (no pad),
// full-K single staging, explicit B double-buffer, tail stages input once.

typedef _Float16 f16x8 __attribute__((ext_vector_type(8)));
typedef float    f32x4 __attribute__((ext_vector_type(4)));
typedef unsigned short u16;
typedef unsigned int   u32;

__device__ __forceinline__ u16 f2h(float f) {
  union { _Float16 h; u16 u; } c; c.h = (_Float16)f; return c.u;
}

__device__ __forceinline__ void store8(u16* dst, const u16* o) {
  uint4 v;
  v.x = (u32)o[0] | ((u32)o[1] << 16);
  v.y = (u32)o[2] | ((u32)o[3] << 16);
  v.z = (u32)o[4] | ((u32)o[5] << 16);
  v.w = (u32)o[6] | ((u32)o[7] << 16);
  *(uint4*)dst = v;
}

// ---------------------------------------------------------------------------
// Weight repack to MFMA B-fragment order (one coalesced dwordx4 per lane):
// WbP frag idx ((l*9+tap)*8+kc)*16+ct, frag = [lane][8]: B[k=kc*32+q*8+j][co=ct*16+rr]
// WtP: same per ab (spatially flipped), WmP: 8 kc x 5 nt.
// ---------------------------------------------------------------------------
__global__ void prep_weights(const float* __restrict__ Wc, const float* __restrict__ Wt,
                             const float* __restrict__ Wm,
                             u16* __restrict__ WbP, u16* __restrict__ WtP,
                             u16* __restrict__ WmP) {
  int id = blockIdx.x * 256 + threadIdx.x;
  u16 o[8];
  if (id < 294912) {
    int li = id & 63; int rest = id >> 6;
    int ct = rest & 15; rest >>= 4;
    int kc = rest & 7;  rest >>= 3;          // rest = l*9+tap (0..35)
    int co  = ct * 16 + (li & 15);
    int ci0 = kc * 32 + (li >> 4) * 8;
#pragma unroll
    for (int j = 0; j < 8; j++) o[j] = f2h(Wc[(rest * 256 + ci0 + j) * 256 + co]);
    store8(&WbP[id * 8], o);
  } else if (id < 327680) {
    int id2 = id - 294912;
    int li = id2 & 63; int rest = id2 >> 6;
    int ct = rest & 15; rest >>= 4;
    int kc = rest & 7;  rest >>= 3;          // rest = ab (0..3)
    int srcq = 3 - rest;                     // kernel flip for conv_transpose
    int co  = ct * 16 + (li & 15);
    int ci0 = kc * 32 + (li >> 4) * 8;
#pragma unroll
    for (int j = 0; j < 8; j++) o[j] = f2h(Wt[(srcq * 256 + ci0 + j) * 256 + co]);
    store8(&WtP[id2 * 8], o);
  } else if (id < 330240) {
    int id3 = id - 327680;
    int li = id3 & 63; int rest = id3 >> 6;  // 0..39
    int kc = rest / 5, nt = rest % 5;
    int nc  = nt * 16 + (li & 15);
    int ci0 = kc * 32 + (li >> 4) * 8;
#pragma unroll
    for (int j = 0; j < 8; j++) o[j] = f2h(Wm[(ci0 + j) * 80 + nc]);
    store8(&WmP[id3 * 8], o);
  }
}

// ---------------------------------------------------------------------------
// conv3x3 SAME, 256->256, relu(x+b). Block = (roi, 64-px chunk).
// Stages 96 rows (halo window) x 256 ch fp16, XOR-swizzled 16B chunks
// (chunk' = chunk ^ (row&7), row stride 512B) -> conflict-free b128 r/w.
// Row 96 = 512B zero page for halo/pad reads. 4 waves x (4 mt x 4 nf).
// ---------------------------------------------------------------------------
template <bool INF32>
__global__ __launch_bounds__(256, 3)
void conv_layer(const void* __restrict__ in_, const u16* __restrict__ WbP,
                const float* __restrict__ bc, u16* __restrict__ out, int layer) {
  __shared__ u16 sA[97 * 256];               // 49664 B
  const int tid = threadIdx.x;
  const int w = tid >> 6, lane = tid & 63, q = lane >> 4, r = lane & 15;
  const int roi = blockIdx.x, P0 = blockIdx.y * 64;
  const int pixbase = P0 - 15;

  if (tid < 128) ((u32*)(sA + 96 * 256))[tid] = 0u;

  if (INF32) {
    const float* xin = (const float*)in_;
    for (int i = tid; i < 3072; i += 256) {
      int lp = i >> 5, c = i & 31;
      int g = pixbase + lp;
      uint4 d = {0u, 0u, 0u, 0u};
      if ((u32)g < 196u) {
        const float* s = &xin[((roi * 196 + g) << 8) + c * 8];
        float4 v0 = *(const float4*)s;
        float4 v1 = *(const float4*)(s + 4);
        d.x = (u32)f2h(v0.x) | ((u32)f2h(v0.y) << 16);
        d.y = (u32)f2h(v0.z) | ((u32)f2h(v0.w) << 16);
        d.z = (u32)f2h(v1.x) | ((u32)f2h(v1.y) << 16);
        d.w = (u32)f2h(v1.z) | ((u32)f2h(v1.w) << 16);
      }
      *(uint4*)((char*)sA + lp * 512 + ((c ^ (lp & 7)) << 4)) = d;
    }
  } else {
    const u16* yin = (const u16*)in_;
    for (int i = tid; i < 3072; i += 256) {
      int lp = i >> 5, c = i & 31;
      int g = pixbase + lp;
      uint4 d = {0u, 0u, 0u, 0u};
      if ((u32)g < 196u) d = *(const uint4*)&yin[((roi * 196 + g) << 8) + c * 8];
      *(uint4*)((char*)sA + lp * 512 + ((c ^ (lp & 7)) << 4)) = d;
    }
  }

  int py[4], px[4], lpb[4];
#pragma unroll
  for (int mt = 0; mt < 4; mt++) {
    int p = P0 + mt * 16 + r;
    py[mt] = p / 14; px[mt] = p % 14;
    lpb[mt] = mt * 16 + r + 15;              // lp = lpb + dy*14+dx (identity)
  }
  f32x4 acc[4][4];
#pragma unroll
  for (int mt = 0; mt < 4; mt++)
#pragma unroll
    for (int nf = 0; nf < 4; nf++) acc[mt][nf] = (f32x4){0.f, 0.f, 0.f, 0.f};

  __syncthreads();

  const u16* Bp = WbP + (size_t)layer * 589824;   // 9*8*16 frags * 512 u16
  const u32 q16 = (u32)(q << 4);
  u32 base[4], key[4];

  auto setoffs = [&](int t) {
    int tap = t >> 3;
    int dy = tap / 3 - 1, dx = tap % 3 - 1;
    int d = dy * 14 + dx;
#pragma unroll
    for (int mt = 0; mt < 4; mt++) {
      int ny = py[mt] + dy, nx = px[mt] + dx;
      bool v = ((u32)ny < 14u) && ((u32)nx < 14u);
      int lp = lpb[mt] + d;
      base[mt] = v ? (u32)(lp * 512) : (u32)(96 * 512);
      key[mt]  = v ? (u32)((lp & 7) << 4) : 0u;
    }
  };
  auto loadb = [&](f16x8* b, int t) {
#pragma unroll
    for (int nf = 0; nf < 4; nf++)
      b[nf] = *(const f16x8*)&Bp[(t * 16 + w * 4 + nf) * 512 + lane * 8];
  };
  auto step = [&](int t, const f16x8* b) {
    int kk = t & 7;
    u32 kq = (u32)(kk << 6) | q16;
    f16x8 a[4];
#pragma unroll
    for (int mt = 0; mt < 4; mt++)
      a[mt] = *(const f16x8*)((const char*)sA + (base[mt] + (kq ^ key[mt])));
#pragma unroll
    for (int mt = 0; mt < 4; mt++)
#pragma unroll
      for (int nf = 0; nf < 4; nf++)
        acc[mt][nf] = __builtin_amdgcn_mfma_f32_16x16x32_f16(a[mt], b[nf], acc[mt][nf], 0, 0, 0);
  };

  f16x8 bcur[4], bnxt[4];
  setoffs(0);
  loadb(bcur, 0);
#pragma unroll 4
  for (int t = 0; t < 72; t += 2) {
    loadb(bnxt, t + 1);
    step(t, bcur);
    loadb(bcur, (t + 2 < 72) ? (t + 2) : 71);
    step(t + 1, bnxt);
    if (((t + 2) & 7) == 0 && (t + 2) < 72) setoffs(t + 2);
  }

  float bias[4];
#pragma unroll
  for (int nf = 0; nf < 4; nf++) bias[nf] = bc[layer * 256 + (w * 4 + nf) * 16 + r];
#pragma unroll
  for (int mt = 0; mt < 4; mt++) {
#pragma unroll
    for (int jj = 0; jj < 4; jj++) {
      int p = P0 + mt * 16 + q * 4 + jj;     // C/D: row = q*4+reg, col = r
      if (p < 196) {
#pragma unroll
        for (int nf = 0; nf < 4; nf++) {
          float v = fmaxf(acc[mt][nf][jj] + bias[nf], 0.f);
          out[((roi * 196 + p) << 8) + (w * 4 + nf) * 16 + r] = f2h(v);
        }
      }
    }
  }
}

// ---------------------------------------------------------------------------
// Fused transpose-conv (per-quadrant 1x1 GEMM) + relu + 1x1 mask conv.
// Block = (roi, 64-px chunk). Input staged ONCE (no halo needed), then the 4
// quadrants processed sequentially: GEMM vs WtP[ab] -> relu+bias -> swizzled
// LDS T-tile -> mask GEMM (N=80) -> global. LDS 64 KB -> 2 blocks/CU.
// ---------------------------------------------------------------------------
__global__ __launch_bounds__(256, 2)
void tail_fused(const u16* __restrict__ y4, const u16* __restrict__ WtP,
                const u16* __restrict__ WmP, const float* __restrict__ bt,
                const float* __restrict__ bm, float* __restrict__ out) {
  __shared__ u16 sIn[64 * 256];
  __shared__ u16 sT[64 * 256];
  const int tid = threadIdx.x;
  const int w = tid >> 6, lane = tid & 63, q = lane >> 4, r = lane & 15;
  const int roi = blockIdx.x, P0 = blockIdx.y * 64;

  for (int i = tid; i < 2048; i += 256) {
    int lp = i >> 5, c = i & 31;
    int g = P0 + lp;
    uint4 d = {0u, 0u, 0u, 0u};
    if (g < 196) d = *(const uint4*)&y4[((roi * 196 + g) << 8) + c * 8];
    *(uint4*)((char*)sIn + lp * 512 + ((c ^ (lp & 7)) << 4)) = d;
  }
  __syncthreads();

  float btv[4];
#pragma unroll
  for (int nf = 0; nf < 4; nf++) btv[nf] = bt[(w * 4 + nf) * 16 + r];
  float bmv[5];
#pragma unroll
  for (int nt = 0; nt < 5; nt++) bmv[nt] = bm[nt * 16 + r];
  const u32 q16 = (u32)(q << 4);

  for (int ab = 0; ab < 4; ab++) {
    f32x4 acc[4][4];
#pragma unroll
    for (int mt = 0; mt < 4; mt++)
#pragma unroll
      for (int nf = 0; nf < 4; nf++) acc[mt][nf] = (f32x4){0.f, 0.f, 0.f, 0.f};

#pragma unroll
    for (int kk = 0; kk < 8; kk++) {
      f16x8 b[4];
#pragma unroll
      for (int nf = 0; nf < 4; nf++)
        b[nf] = *(const f16x8*)&WtP[((ab * 8 + kk) * 16 + w * 4 + nf) * 512 + lane * 8];
      u32 kq = (u32)(kk << 6) | q16;
#pragma unroll
      for (int mt = 0; mt < 4; mt++) {
        int lp = mt * 16 + r;
        f16x8 a = *(const f16x8*)((const char*)sIn + lp * 512 + ((kq ^ (u32)((lp & 7) << 4))));
#pragma unroll
        for (int nf = 0; nf < 4; nf++)
          acc[mt][nf] = __builtin_amdgcn_mfma_f32_16x16x32_f16(a, b[nf], acc[mt][nf], 0, 0, 0);
      }
    }

    if (ab) __syncthreads();                 // prior mask-GEMM reads of sT done
#pragma unroll
    for (int mt = 0; mt < 4; mt++) {
#pragma unroll
      for (int jj = 0; jj < 4; jj++) {
        int row = mt * 16 + q * 4 + jj;
#pragma unroll
        for (int nf = 0; nf < 4; nf++) {
          int ch = (w * 4 + nf) * 16 + r;
          int c = ch >> 3, e = ch & 7;
          float v = fmaxf(acc[mt][nf][jj] + btv[nf], 0.f);
          *(u16*)((char*)sT + row * 512 + ((c ^ (row & 7)) << 4) + e * 2) = f2h(v);
        }
      }
    }
    __syncthreads();

    // mask GEMM: wave w owns rows [w*16, w*16+16), 5 N-tiles of 16 (=80).
    f32x4 a2[5];
#pragma unroll
    for (int nt = 0; nt < 5; nt++) a2[nt] = (f32x4){0.f, 0.f, 0.f, 0.f};
    {
      int lp = w * 16 + r;
      u32 rowbase = (u32)(lp * 512), rkey = (u32)((lp & 7) << 4);
#pragma unroll
      for (int kk = 0; kk < 8; kk++) {
        u32 kq = (u32)(kk << 6) | q16;
        f16x8 af = *(const f16x8*)((const char*)sT + rowbase + (kq ^ rkey));
#pragma unroll
        for (int nt = 0; nt < 5; nt++) {
          f16x8 bw = *(const f16x8*)&WmP[((kk * 5 + nt) * 64 + lane) * 8];
          a2[nt] = __builtin_amdgcn_mfma_f32_16x16x32_f16(af, bw, a2[nt], 0, 0, 0);
        }
      }
    }
    const int a_ = ab >> 1, b_ = ab & 1;
#pragma unroll
    for (int jj = 0; jj < 4; jj++) {
      int p = P0 + w * 16 + q * 4 + jj;
      if (p < 196) {
        int y = p / 14, x = p % 14;
        int obase = roi * 62720 + (2 * y + a_) * 2240 + (2 * x + b_) * 80;
#pragma unroll
        for (int nt = 0; nt < 5; nt++) out[obase + nt * 16 + r] = a2[nt][jj] + bmv[nt];
      }
    }
  }
}

// ---------------------------------------------------------------------------
extern "C" void kernel_launch(void* const* d_in, const int* in_sizes, int n_in,
                              void* d_out, int out_size, void* d_ws, size_t ws_size,
                              hipStream_t stream) {
  const float* x  = (const float*)d_in[0];
  const float* Wc = (const float*)d_in[1];
  const float* bc = (const float*)d_in[2];
  const float* Wt = (const float*)d_in[3];
  const float* bt = (const float*)d_in[4];
  const float* Wm = (const float*)d_in[5];
  const float* bm = (const float*)d_in[6];
  float* out = (float*)d_out;

  char* ws = (char*)d_ws;
  u16* WbP = (u16*)(ws);                         // 4,718,592 B
  u16* WtP = (u16*)(ws + 4718592);               //   524,288 B
  u16* WmP = (u16*)(ws + 5242880);               //    40,960 B
  u16* yA  = (u16*)(ws + 6291456);               // 102,760,448 B
  u16* yB  = (u16*)(ws + 6291456 + 102760448);   // 102,760,448 B

  prep_weights<<<1290, 256, 0, stream>>>(Wc, Wt, Wm, WbP, WtP, WmP);

  dim3 cg(1024, 4);
  conv_layer<true ><<<cg, 256, 0, stream>>>(x,  WbP, bc, yA, 0);
  conv_layer<false><<<cg, 256, 0, stream>>>(yA, WbP, bc, yB, 1);
  conv_layer<false><<<cg, 256, 0, stream>>>(yB, WbP, bc, yA, 2);
  conv_layer<false><<<cg, 256, 0, stream>>>(yA, WbP, bc, yB, 3);

  tail_fused<<<dim3(1024, 4), 256, 0, stream>>>(yB, WtP, WmP, bt, bm, out);
}